// Round 5
// baseline (916.765 us; speedup 1.0000x reference)
//
#include <hip/hip_runtime.h>
#include <hip/hip_bf16.h>

// SPRGraphNet: embed -> SAGEConv x2 (mean aggr) -> global mean pool -> linear head
// N=50000 nodes, E=800000 edges, G=512 graphs, EMB=128, HID=256, NCLS=32. All fp32.

#define EMB   128
#define HID   256
#define NCLS  32
#define DIM   256   // feature width of h at every stage (2*EMB == HID == 256)

// ---------------------------------------------------------------- utility kernels

// Both layers' concat+transpose weight builds in one launch.
// Bt[k*256+o] = k<256 ? wl[o,k] : wr[o,k-256]   (512x256 each)
__global__ void build_bt2(const float* __restrict__ w1l, const float* __restrict__ w1r,
                          const float* __restrict__ w2l, const float* __restrict__ w2r,
                          float* __restrict__ bt1, float* __restrict__ bt2) {
    int tid = blockIdx.x * 256 + threadIdx.x;   // 2*512*256 threads
    int which = tid >> 17;                      // 0 -> layer1, 1 -> layer2
    int r = tid & 0x1FFFF;
    int k = r >> 8, o = r & 255;
    const float* wl = which ? w2l : w1l;
    const float* wr = which ? w2r : w1r;
    float* bt = which ? bt2 : bt1;
    bt[r] = (k < 256) ? wl[o * 256 + k] : wr[o * 256 + (k - 256)];
}

// h0[n] = concat(shape_emb[x[n,0]], color_emb[x[n,1]])  -- float4 per thread
__global__ void embed_kernel(const int* __restrict__ x,
                             const float* __restrict__ se, const float* __restrict__ ce,
                             float* __restrict__ h, int n_nodes) {
    int tid = blockIdx.x * 256 + threadIdx.x;   // n_nodes*64 float4 chunks
    if (tid >= n_nodes * 64) return;
    int n = tid >> 6, c = tid & 63;
    const float* src = (c < 32) ? (se + (size_t)x[n * 2] * EMB + c * 4)
                                : (ce + (size_t)x[n * 2 + 1] * EMB + (c - 32) * 4);
    ((float4*)h)[tid] = *(const float4*)src;
}

// ---------------------------------------------------------------- CSR build

__global__ void count_deg(const int* __restrict__ dst, int* __restrict__ deg, int E) {
    int e = blockIdx.x * 256 + threadIdx.x;
    if (e < E) atomicAdd(&deg[dst[e]], 1);
}

__global__ void scan_block(const int* __restrict__ deg, int* __restrict__ rowptr,
                           int* __restrict__ bsums, int n) {
    __shared__ int s[256];
    int t = threadIdx.x;
    int i = blockIdx.x * 256 + t;
    int v = (i < n) ? deg[i] : 0;
    s[t] = v; __syncthreads();
    for (int off = 1; off < 256; off <<= 1) {
        int x = (t >= off) ? s[t - off] : 0;
        __syncthreads(); s[t] += x; __syncthreads();
    }
    if (i < n) rowptr[i] = s[t] - v;            // exclusive within block
    if (t == 255) bsums[blockIdx.x] = s[255];
}

__global__ void scan_sums(int* __restrict__ bsums, int nb, int* __restrict__ rowptr,
                          int n, int E) {
    __shared__ int s[256];
    int t = threadIdx.x;
    int v = (t < nb) ? bsums[t] : 0;
    s[t] = v; __syncthreads();
    for (int off = 1; off < 256; off <<= 1) {
        int x = (t >= off) ? s[t - off] : 0;
        __syncthreads(); s[t] += x; __syncthreads();
    }
    if (t < nb) bsums[t] = s[t] - v;            // exclusive block offsets
    if (t == 0) rowptr[n] = E;
}

__global__ void scan_add(int* __restrict__ rowptr, const int* __restrict__ bsums, int n) {
    int i = blockIdx.x * 256 + threadIdx.x;
    if (i < n) rowptr[i] += bsums[i >> 8];
}

__global__ void fill_csr(const int* __restrict__ src, const int* __restrict__ dst,
                         const int* __restrict__ rowptr, int* __restrict__ cursor,
                         int* __restrict__ csr, int E) {
    int e = blockIdx.x * 256 + threadIdx.x;
    if (e >= E) return;
    int d = dst[e];
    int pos = rowptr[d] + atomicAdd(&cursor[d], 1);
    csr[pos] = src[e];
}

// ---------------------------------------------------------------- mean aggregation
// one wave (64 lanes) per node; lane l owns float4 chunk l of the 256-dim row.
__global__ void aggregate(const float* __restrict__ h, const int* __restrict__ rowptr,
                          const int* __restrict__ csr, float* __restrict__ agg, int n_nodes) {
    int wid = (blockIdx.x * 256 + threadIdx.x) >> 6;
    int lane = threadIdx.x & 63;
    if (wid >= n_nodes) return;
    int beg = rowptr[wid], end = rowptr[wid + 1];
    float ax = 0.f, ay = 0.f, az = 0.f, aw = 0.f;
    for (int k = beg; k < end; ++k) {
        int s = csr[k];
        float4 v = ((const float4*)(h + (size_t)s * DIM))[lane];
        ax += v.x; ay += v.y; az += v.z; aw += v.w;
    }
    int d = end - beg;
    float inv = 1.0f / (float)(d > 1 ? d : 1);
    float4 o; o.x = ax * inv; o.y = ay * inv; o.z = az * inv; o.w = aw * inv;
    ((float4*)(agg + (size_t)wid * DIM))[lane] = o;
}

// ---------------------------------------------------------------- fused SAGE GEMM
// Hout[n,o] = relu( sum_k Agg[n,k]*Wl[o,k] + Hin[n,k]*Wr[o,k] + bias[o] )
// A = [Agg | Hin] (M x 512), B = Bt (512 x 256, pre-transposed). 128x128 tile, 8x8 micro.
__global__ void __launch_bounds__(256)
gemm_fused(const float* __restrict__ Agg, const float* __restrict__ Hin,
           const float* __restrict__ Bt, const float* __restrict__ bias,
           float* __restrict__ Hout, int M) {
    __shared__ float As[32 * 132];   // [BK=32][BM=128 +4 pad] transposed A tile
    __shared__ float Bs[32 * 128];   // [BK=32][BN=128]

    int t = threadIdx.x;
    int tx = t & 15, ty = t >> 4;
    int m0 = blockIdx.x * 128;
    int n0 = blockIdx.y * 128;

    float acc[8][8];
#pragma unroll
    for (int i = 0; i < 8; ++i)
#pragma unroll
        for (int j = 0; j < 8; ++j) acc[i][j] = 0.f;

    for (int kt = 0; kt < 16; ++kt) {           // K=512, BK=32
        const float* Asrc = (kt < 8) ? Agg : Hin;
        int kofs = (kt < 8) ? kt * 32 : kt * 32 - 256;
#pragma unroll
        for (int pass = 0; pass < 4; ++pass) {  // A tile: 128 rows x 32 k, transposed
            int row = pass * 32 + (t >> 3);
            int q = t & 7;
            int gr = m0 + row;
            float4 v = make_float4(0.f, 0.f, 0.f, 0.f);
            if (gr < M) v = *(const float4*)&Asrc[(size_t)gr * DIM + kofs + q * 4];
            As[(q * 4 + 0) * 132 + row] = v.x;
            As[(q * 4 + 1) * 132 + row] = v.y;
            As[(q * 4 + 2) * 132 + row] = v.z;
            As[(q * 4 + 3) * 132 + row] = v.w;
        }
#pragma unroll
        for (int pass = 0; pass < 4; ++pass) {  // B tile: 32 k x 128 o, straight
            int k = pass * 8 + (t >> 5);
            int o4 = (t & 31) * 4;
            float4 v = *(const float4*)&Bt[(kt * 32 + k) * 256 + n0 + o4];
            *(float4*)&Bs[k * 128 + o4] = v;
        }
        __syncthreads();
#pragma unroll
        for (int kk = 0; kk < 32; ++kk) {
            float a[8], b[8];
            *(float4*)&a[0] = *(const float4*)&As[kk * 132 + ty * 8];
            *(float4*)&a[4] = *(const float4*)&As[kk * 132 + ty * 8 + 4];
            *(float4*)&b[0] = *(const float4*)&Bs[kk * 128 + tx * 8];
            *(float4*)&b[4] = *(const float4*)&Bs[kk * 128 + tx * 8 + 4];
#pragma unroll
            for (int i = 0; i < 8; ++i)
#pragma unroll
                for (int j = 0; j < 8; ++j)
                    acc[i][j] = fmaf(a[i], b[j], acc[i][j]);
        }
        __syncthreads();
    }

#pragma unroll
    for (int i = 0; i < 8; ++i) {
        int row = m0 + ty * 8 + i;
        if (row >= M) continue;
#pragma unroll
        for (int j = 0; j < 8; ++j) {
            int o = n0 + tx * 8 + j;
            float v = acc[i][j] + bias[o];
            Hout[(size_t)row * DIM + o] = fmaxf(v, 0.f);
        }
    }
}

// ---------------------------------------------------------------- pooling + head

__global__ void pool_kernel(const float* __restrict__ h, const int* __restrict__ batch,
                            float* __restrict__ hg, int n_nodes) {
    int g = blockIdx.x;     // one block per graph, 256 threads = 256 features
    int t = threadIdx.x;
    int lo = 0, hi = n_nodes;
    while (lo < hi) { int mid = (lo + hi) >> 1; if (batch[mid] < g) lo = mid + 1; else hi = mid; }
    int start = lo;
    hi = n_nodes;
    while (lo < hi) { int mid = (lo + hi) >> 1; if (batch[mid] < g + 1) lo = mid + 1; else hi = mid; }
    int end = lo;
    float acc = 0.f;
    for (int n = start; n < end; ++n) acc += h[(size_t)n * DIM + t];
    int c = end - start;
    hg[g * DIM + t] = acc / (float)(c > 1 ? c : 1);
}

__global__ void head_kernel(const float* __restrict__ hg, const float* __restrict__ wc,
                            const float* __restrict__ bc, float* __restrict__ out, int total) {
    int tid = blockIdx.x * 256 + threadIdx.x;   // G*32
    if (tid >= total) return;
    int g = tid >> 5, c = tid & 31;
    const float* hr = hg + (size_t)g * DIM;
    const float* wr = wc + (size_t)c * DIM;
    float acc = bc[c];
    for (int k = 0; k < DIM; ++k) acc = fmaf(hr[k], wr[k], acc);
    out[tid] = acc;
}

// ---------------------------------------------------------------- launch

extern "C" void kernel_launch(void* const* d_in, const int* in_sizes, int n_in,
                              void* d_out, int out_size, void* d_ws, size_t ws_size,
                              hipStream_t stream) {
    const int* x      = (const int*)d_in[0];
    const int* ei     = (const int*)d_in[1];
    const int* batch  = (const int*)d_in[2];
    const float* se   = (const float*)d_in[3];
    const float* ce   = (const float*)d_in[4];
    const float* w1l  = (const float*)d_in[5];
    const float* b1l  = (const float*)d_in[6];
    const float* w1r  = (const float*)d_in[7];
    const float* w2l  = (const float*)d_in[8];
    const float* b2l  = (const float*)d_in[9];
    const float* w2r  = (const float*)d_in[10];
    const float* wc   = (const float*)d_in[11];
    const float* bc   = (const float*)d_in[12];
    float* out = (float*)d_out;

    const int N = in_sizes[0] / 2;
    const int E = in_sizes[1] / 2;
    const int G = out_size / NCLS;
    const int* src = ei;
    const int* dst = ei + E;

    // workspace carve-up (fp32)
    float* hA  = (float*)d_ws;                  // N*256
    float* hB  = hA + (size_t)N * DIM;          // N*256
    float* agg = hB + (size_t)N * DIM;          // N*256
    float* Bt1 = agg + (size_t)N * DIM;         // 512*256
    float* Bt2 = Bt1 + 512 * 256;               // 512*256
    float* hg  = Bt2 + 512 * 256;               // G*256
    int* deg    = (int*)(hg + (size_t)G * DIM); // N
    int* rowptr = deg + N;                      // N+1
    int* cursor = rowptr + (N + 1);             // N
    int* csr    = cursor + N;                   // E
    int* bsums  = csr + E;                      // <=256

    // zero deg + rowptr + cursor in one shot (contiguous)
    hipMemsetAsync(deg, 0, (size_t)(3 * N + 1) * sizeof(int), stream);

    int nwave_blocks = (N * 64 + 255) / 256;            // embed / aggregate grids
    embed_kernel<<<nwave_blocks, 256, 0, stream>>>(x, se, ce, hA, N);

    int eblocks = (E + 255) / 256;
    count_deg<<<eblocks, 256, 0, stream>>>(dst, deg, E);
    int sblocks = (N + 255) / 256;                      // 196
    scan_block<<<sblocks, 256, 0, stream>>>(deg, rowptr, bsums, N);
    scan_sums<<<1, 256, 0, stream>>>(bsums, sblocks, rowptr, N, E);
    scan_add<<<sblocks, 256, 0, stream>>>(rowptr, bsums, N);
    fill_csr<<<eblocks, 256, 0, stream>>>(src, dst, rowptr, cursor, csr, E);

    build_bt2<<<1024, 256, 0, stream>>>(w1l, w1r, w2l, w2r, Bt1, Bt2);

    dim3 ggrid((N + 127) / 128, 2);

    // layer 1: hA(h0) -> agg -> hB(h1)
    aggregate<<<(N * 64 + 255) / 256, 256, 0, stream>>>(hA, rowptr, csr, agg, N);
    gemm_fused<<<ggrid, 256, 0, stream>>>(agg, hA, Bt1, b1l, hB, N);

    // layer 2: hB(h1) -> agg -> hA(h2)
    aggregate<<<(N * 64 + 255) / 256, 256, 0, stream>>>(hB, rowptr, csr, agg, N);
    gemm_fused<<<ggrid, 256, 0, stream>>>(agg, hB, Bt2, b2l, hA, N);

    pool_kernel<<<G, 256, 0, stream>>>(hA, batch, hg, N);
    head_kernel<<<(G * NCLS + 255) / 256, 256, 0, stream>>>(hg, wc, bc, out, G * NCLS);
}

// Round 6
// 574.537 us; speedup vs baseline: 1.5957x; 1.5957x over previous
//
#include <hip/hip_runtime.h>
#include <hip/hip_bf16.h>

// SPRGraphNet: embed -> SAGEConv x2 (mean aggr) -> global mean pool -> linear head
// N=50000, E=800000, G=512, EMB=128, HID=256, NCLS=32. fp32 in/out.
// GEMM path: bf16 split-precision MFMA (hi/lo), 3-product, ~1e-5 rel err.

#define EMB   128
#define HID   256
#define NCLS  32
#define DIM   256   // feature width everywhere (2*EMB == HID == 256)

typedef __attribute__((ext_vector_type(8))) short short8v;   // 8 bf16 = 4 VGPR (MFMA A/B frag)
typedef __attribute__((ext_vector_type(4))) float float4v;   // MFMA C/D frag

__device__ __forceinline__ unsigned short f2bf(float f) {    // RNE fp32->bf16 (normals)
    unsigned int u = __float_as_uint(f);
    unsigned int r = u + 0x7FFFu + ((u >> 16) & 1u);
    return (unsigned short)(r >> 16);
}
__device__ __forceinline__ float bf2f(unsigned short s) {
    return __uint_as_float(((unsigned int)s) << 16);
}

// ---------------------------------------------------------------- weight precompute
// Bq[k][o] = k<256 ? wl[o,k] : wr[o,k-256], stored as bf16 hi/lo in MFMA-fragment-
// native layout: idx = ((k>>3)*256 + o)*8 + (k&7)  (lane reads 8 consecutive k).
__global__ void build_bq(const float* __restrict__ wl, const float* __restrict__ wr,
                         unsigned short* __restrict__ bhi, unsigned short* __restrict__ blo) {
    int tid = blockIdx.x * 256 + threadIdx.x;   // 512*256 = 131072 threads
    int k = tid >> 8, o = tid & 255;
    float v = (k < 256) ? wl[o * 256 + k] : wr[o * 256 + (k - 256)];
    unsigned short h = f2bf(v);
    unsigned short l = f2bf(v - bf2f(h));
    int idx = (((k >> 3) * 256) + o) * 8 + (k & 7);
    bhi[idx] = h;
    blo[idx] = l;
}

// h0[n] = concat(shape_emb[x[n,0]], color_emb[x[n,1]])  -- float4 per thread
__global__ void embed_kernel(const int* __restrict__ x,
                             const float* __restrict__ se, const float* __restrict__ ce,
                             float* __restrict__ h, int n_nodes) {
    int tid = blockIdx.x * 256 + threadIdx.x;
    if (tid >= n_nodes * 64) return;
    int n = tid >> 6, c = tid & 63;
    const float* src = (c < 32) ? (se + (size_t)x[n * 2] * EMB + c * 4)
                                : (ce + (size_t)x[n * 2 + 1] * EMB + (c - 32) * 4);
    ((float4*)h)[tid] = *(const float4*)src;
}

// ---------------------------------------------------------------- CSR build

__global__ void count_deg(const int* __restrict__ dst, int* __restrict__ deg, int E) {
    int e = blockIdx.x * 256 + threadIdx.x;
    if (e < E) atomicAdd(&deg[dst[e]], 1);
}

__global__ void scan_block(const int* __restrict__ deg, int* __restrict__ rowptr,
                           int* __restrict__ bsums, int n) {
    __shared__ int s[256];
    int t = threadIdx.x;
    int i = blockIdx.x * 256 + t;
    int v = (i < n) ? deg[i] : 0;
    s[t] = v; __syncthreads();
    for (int off = 1; off < 256; off <<= 1) {
        int x = (t >= off) ? s[t - off] : 0;
        __syncthreads(); s[t] += x; __syncthreads();
    }
    if (i < n) rowptr[i] = s[t] - v;
    if (t == 255) bsums[blockIdx.x] = s[255];
}

__global__ void scan_sums(int* __restrict__ bsums, int nb, int* __restrict__ rowptr,
                          int n, int E) {
    __shared__ int s[256];
    int t = threadIdx.x;
    int v = (t < nb) ? bsums[t] : 0;
    s[t] = v; __syncthreads();
    for (int off = 1; off < 256; off <<= 1) {
        int x = (t >= off) ? s[t - off] : 0;
        __syncthreads(); s[t] += x; __syncthreads();
    }
    if (t < nb) bsums[t] = s[t] - v;
    if (t == 0) rowptr[n] = E;
}

__global__ void scan_add(int* __restrict__ rowptr, const int* __restrict__ bsums, int n) {
    int i = blockIdx.x * 256 + threadIdx.x;
    if (i < n) rowptr[i] += bsums[i >> 8];
}

__global__ void fill_csr(const int* __restrict__ src, const int* __restrict__ dst,
                         const int* __restrict__ rowptr, int* __restrict__ cursor,
                         int* __restrict__ csr, int E) {
    int e = blockIdx.x * 256 + threadIdx.x;
    if (e >= E) return;
    int d = dst[e];
    int pos = rowptr[d] + atomicAdd(&cursor[d], 1);
    csr[pos] = src[e];
}

// ---------------------------------------------------------------- mean aggregation
__global__ void aggregate(const float* __restrict__ h, const int* __restrict__ rowptr,
                          const int* __restrict__ csr, float* __restrict__ agg, int n_nodes) {
    int wid = (blockIdx.x * 256 + threadIdx.x) >> 6;
    int lane = threadIdx.x & 63;
    if (wid >= n_nodes) return;
    int beg = rowptr[wid], end = rowptr[wid + 1];
    float ax = 0.f, ay = 0.f, az = 0.f, aw = 0.f;
    for (int k = beg; k < end; ++k) {
        int s = csr[k];
        float4 v = ((const float4*)(h + (size_t)s * DIM))[lane];
        ax += v.x; ay += v.y; az += v.z; aw += v.w;
    }
    int d = end - beg;
    float inv = 1.0f / (float)(d > 1 ? d : 1);
    float4 o; o.x = ax * inv; o.y = ay * inv; o.z = az * inv; o.w = aw * inv;
    ((float4*)(agg + (size_t)wid * DIM))[lane] = o;
}

// ---------------------------------------------------------------- MFMA SAGE GEMM
// Hout[m,n] = relu( sum_k [Agg|Hin][m,k] * Bq[k,n] + bias[n] ),  M x 512 x 256.
// BM=64, BN=256 (full N -> A read once), BK=32. 4 waves, each one 64x64 tile.
// A: fp32 -> bf16 hi/lo converted during LDS staging ([64][40] ushort, 2-way max).
// B: pre-split bf16 hi/lo in fragment-native layout, frag = one dwordx4 from L2.
// 3 MFMAs per frag pair: hi*hi + hi*lo + lo*hi (lo*lo ~ 2^-18 dropped).
__global__ void __launch_bounds__(256)
gemm_mfma(const float* __restrict__ Agg, const float* __restrict__ Hin,
          const unsigned short* __restrict__ Bhi, const unsigned short* __restrict__ Blo,
          const float* __restrict__ bias, float* __restrict__ Hout, int M) {
    __shared__ __align__(16) unsigned short As_hi[64 * 40];   // [row][k(32)+pad(8)]
    __shared__ __align__(16) unsigned short As_lo[64 * 40];

    const int t = threadIdx.x;
    const int w = t >> 6, lane = t & 63;
    const int lrow = lane & 15, koct = lane >> 4;   // MFMA lane decomposition
    const int nw = w * 64;                          // wave's N-offset
    const int m0 = blockIdx.x * 64;

    float4v acc[4][4];
#pragma unroll
    for (int i = 0; i < 4; ++i)
#pragma unroll
        for (int j = 0; j < 4; ++j) acc[i][j] = (float4v){0.f, 0.f, 0.f, 0.f};

    const int sr = t >> 2;            // staging: row 0..63
    const int sc = (t & 3) * 8;       // staging: k-offset 0,8,16,24
    const int gr = m0 + sr;
    const bool valid = (gr < M);
    const size_t arow = (size_t)gr * DIM;

#pragma unroll 1
    for (int kt = 0; kt < 16; ++kt) {             // K=512, BK=32
        // ---- stage A tile (fp32 -> bf16 hi/lo) ----
        const float* __restrict__ Ap = ((kt < 8) ? Agg : Hin) + arow + ((kt & 7) * 32 + sc);
        float4 v0 = make_float4(0.f, 0.f, 0.f, 0.f), v1 = v0;
        if (valid) { v0 = *(const float4*)Ap; v1 = *(const float4*)(Ap + 4); }
        float fv[8] = {v0.x, v0.y, v0.z, v0.w, v1.x, v1.y, v1.z, v1.w};
        unsigned short hs[8], ls[8];
#pragma unroll
        for (int i = 0; i < 8; ++i) {
            hs[i] = f2bf(fv[i]);
            ls[i] = f2bf(fv[i] - bf2f(hs[i]));
        }
        *(ushort4*)&As_hi[sr * 40 + sc]     = make_ushort4(hs[0], hs[1], hs[2], hs[3]);
        *(ushort4*)&As_hi[sr * 40 + sc + 4] = make_ushort4(hs[4], hs[5], hs[6], hs[7]);
        *(ushort4*)&As_lo[sr * 40 + sc]     = make_ushort4(ls[0], ls[1], ls[2], ls[3]);
        *(ushort4*)&As_lo[sr * 40 + sc + 4] = make_ushort4(ls[4], ls[5], ls[6], ls[7]);
        __syncthreads();

        // ---- fragments ----
        const int kg = kt * 4 + koct;             // global k-octet index
        short8v bh[4], bl[4], ah[4], al[4];
#pragma unroll
        for (int nt = 0; nt < 4; ++nt) {          // B direct from L2, coalesced dwordx4
            size_t bofs = ((size_t)kg * 256 + (nw + nt * 16 + lrow)) * 8;
            bh[nt] = *(const short8v*)(Bhi + bofs);
            bl[nt] = *(const short8v*)(Blo + bofs);
        }
#pragma unroll
        for (int mt = 0; mt < 4; ++mt) {          // A from LDS, ds_read_b128
            int aofs = (mt * 16 + lrow) * 40 + koct * 8;
            ah[mt] = *(const short8v*)&As_hi[aofs];
            al[mt] = *(const short8v*)&As_lo[aofs];
        }
#pragma unroll
        for (int mt = 0; mt < 4; ++mt)
#pragma unroll
            for (int nt = 0; nt < 4; ++nt) {
                acc[mt][nt] = __builtin_amdgcn_mfma_f32_16x16x32_bf16(ah[mt], bh[nt], acc[mt][nt], 0, 0, 0);
                acc[mt][nt] = __builtin_amdgcn_mfma_f32_16x16x32_bf16(ah[mt], bl[nt], acc[mt][nt], 0, 0, 0);
                acc[mt][nt] = __builtin_amdgcn_mfma_f32_16x16x32_bf16(al[mt], bh[nt], acc[mt][nt], 0, 0, 0);
            }
        __syncthreads();
    }

    // ---- epilogue: bias + relu, C/D layout col=lane&15, row=(lane>>4)*4+reg ----
    float bv[4];
#pragma unroll
    for (int nt = 0; nt < 4; ++nt) bv[nt] = bias[nw + nt * 16 + lrow];

#pragma unroll
    for (int mt = 0; mt < 4; ++mt) {
#pragma unroll
        for (int r = 0; r < 4; ++r) {
            int grow = m0 + mt * 16 + koct * 4 + r;
            if (grow >= M) continue;
#pragma unroll
            for (int nt = 0; nt < 4; ++nt) {
                float vv = acc[mt][nt][r] + bv[nt];
                Hout[(size_t)grow * DIM + nw + nt * 16 + lrow] = fmaxf(vv, 0.f);
            }
        }
    }
}

// ---------------------------------------------------------------- pooling + head

__global__ void pool_kernel(const float* __restrict__ h, const int* __restrict__ batch,
                            float* __restrict__ hg, int n_nodes) {
    int g = blockIdx.x;
    int t = threadIdx.x;
    int lo = 0, hi = n_nodes;
    while (lo < hi) { int mid = (lo + hi) >> 1; if (batch[mid] < g) lo = mid + 1; else hi = mid; }
    int start = lo;
    hi = n_nodes;
    while (lo < hi) { int mid = (lo + hi) >> 1; if (batch[mid] < g + 1) lo = mid + 1; else hi = mid; }
    int end = lo;
    float acc = 0.f;
    for (int n = start; n < end; ++n) acc += h[(size_t)n * DIM + t];
    int c = end - start;
    hg[g * DIM + t] = acc / (float)(c > 1 ? c : 1);
}

__global__ void head_kernel(const float* __restrict__ hg, const float* __restrict__ wc,
                            const float* __restrict__ bc, float* __restrict__ out, int total) {
    int tid = blockIdx.x * 256 + threadIdx.x;
    if (tid >= total) return;
    int g = tid >> 5, c = tid & 31;
    const float* hr = hg + (size_t)g * DIM;
    const float* wr = wc + (size_t)c * DIM;
    float acc = bc[c];
    for (int k = 0; k < DIM; ++k) acc = fmaf(hr[k], wr[k], acc);
    out[tid] = acc;
}

// ---------------------------------------------------------------- launch

extern "C" void kernel_launch(void* const* d_in, const int* in_sizes, int n_in,
                              void* d_out, int out_size, void* d_ws, size_t ws_size,
                              hipStream_t stream) {
    const int* x      = (const int*)d_in[0];
    const int* ei     = (const int*)d_in[1];
    const int* batch  = (const int*)d_in[2];
    const float* se   = (const float*)d_in[3];
    const float* ce   = (const float*)d_in[4];
    const float* w1l  = (const float*)d_in[5];
    const float* b1l  = (const float*)d_in[6];
    const float* w1r  = (const float*)d_in[7];
    const float* w2l  = (const float*)d_in[8];
    const float* b2l  = (const float*)d_in[9];
    const float* w2r  = (const float*)d_in[10];
    const float* wc   = (const float*)d_in[11];
    const float* bc   = (const float*)d_in[12];
    float* out = (float*)d_out;

    const int N = in_sizes[0] / 2;
    const int E = in_sizes[1] / 2;
    const int G = out_size / NCLS;
    const int* src = ei;
    const int* dst = ei + E;

    // workspace carve-up
    float* hA  = (float*)d_ws;                              // N*256 f32
    float* hB  = hA + (size_t)N * DIM;                      // N*256 f32
    float* agg = hB + (size_t)N * DIM;                      // N*256 f32
    unsigned short* B1hi = (unsigned short*)(agg + (size_t)N * DIM);  // 64*256*8
    unsigned short* B1lo = B1hi + 131072;
    unsigned short* B2hi = B1lo + 131072;
    unsigned short* B2lo = B2hi + 131072;
    float* hg  = (float*)(B2lo + 131072);                   // G*256
    int* deg    = (int*)(hg + (size_t)G * DIM);             // N
    int* rowptr = deg + N;                                  // N+1
    int* cursor = rowptr + (N + 1);                         // N
    int* csr    = cursor + N;                               // E
    int* bsums  = csr + E;                                  // <=256

    hipMemsetAsync(deg, 0, (size_t)(3 * N + 1) * sizeof(int), stream);

    int nwave_blocks = (N * 64 + 255) / 256;
    embed_kernel<<<nwave_blocks, 256, 0, stream>>>(x, se, ce, hA, N);

    int eblocks = (E + 255) / 256;
    count_deg<<<eblocks, 256, 0, stream>>>(dst, deg, E);
    int sblocks = (N + 255) / 256;
    scan_block<<<sblocks, 256, 0, stream>>>(deg, rowptr, bsums, N);
    scan_sums<<<1, 256, 0, stream>>>(bsums, sblocks, rowptr, N, E);
    scan_add<<<sblocks, 256, 0, stream>>>(rowptr, bsums, N);
    fill_csr<<<eblocks, 256, 0, stream>>>(src, dst, rowptr, cursor, csr, E);

    build_bq<<<512, 256, 0, stream>>>(w1l, w1r, B1hi, B1lo);
    build_bq<<<512, 256, 0, stream>>>(w2l, w2r, B2hi, B2lo);

    int gblocks = (N + 63) / 64;

    // layer 1: hA(h0) -> agg -> hB(h1)
    aggregate<<<(N * 64 + 255) / 256, 256, 0, stream>>>(hA, rowptr, csr, agg, N);
    gemm_mfma<<<gblocks, 256, 0, stream>>>(agg, hA, B1hi, B1lo, b1l, hB, N);

    // layer 2: hB(h1) -> agg -> hA(h2)
    aggregate<<<(N * 64 + 255) / 256, 256, 0, stream>>>(hB, rowptr, csr, agg, N);
    gemm_mfma<<<gblocks, 256, 0, stream>>>(agg, hB, B2hi, B2lo, b2l, hA, N);

    pool_kernel<<<G, 256, 0, stream>>>(hA, batch, hg, N);
    head_kernel<<<(G * NCLS + 255) / 256, 256, 0, stream>>>(hg, wc, bc, out, G * NCLS);
}

// Round 7
// 462.017 us; speedup vs baseline: 1.9843x; 1.2435x over previous
//
#include <hip/hip_runtime.h>
#include <hip/hip_bf16.h>

// SPRGraphNet: embed -> SAGEConv x2 (mean aggr) -> global mean pool -> linear head
// N=50000, E=800000, G=512, EMB=128, HID=256, NCLS=32. fp32 in/out.
// Feature table h stored bf16 (halves gather traffic); GEMM: bf16 split MFMA.

#define EMB   128
#define HID   256
#define NCLS  32
#define DIM   256   // feature width everywhere (2*EMB == HID == 256)

typedef __attribute__((ext_vector_type(8))) short short8v;   // 8 bf16 = 4 VGPR (MFMA A/B frag)
typedef __attribute__((ext_vector_type(4))) float float4v;   // MFMA C/D frag

__device__ __forceinline__ unsigned short f2bf(float f) {    // RNE fp32->bf16 (normals)
    unsigned int u = __float_as_uint(f);
    unsigned int r = u + 0x7FFFu + ((u >> 16) & 1u);
    return (unsigned short)(r >> 16);
}
__device__ __forceinline__ float bf2f(unsigned short s) {
    return __uint_as_float(((unsigned int)s) << 16);
}

// ---------------------------------------------------------------- weight precompute
// Bq[k][o] = k<256 ? wl[o,k] : wr[o,k-256], bf16 hi/lo, fragment-native:
// idx = ((k>>3)*256 + o)*8 + (k&7)
__global__ void build_bq(const float* __restrict__ wl, const float* __restrict__ wr,
                         unsigned short* __restrict__ bhi, unsigned short* __restrict__ blo) {
    int tid = blockIdx.x * 256 + threadIdx.x;   // 512*256 threads
    int k = tid >> 8, o = tid & 255;
    float v = (k < 256) ? wl[o * 256 + k] : wr[o * 256 + (k - 256)];
    unsigned short h = f2bf(v);
    unsigned short l = f2bf(v - bf2f(h));
    int idx = (((k >> 3) * 256) + o) * 8 + (k & 7);
    bhi[idx] = h;
    blo[idx] = l;
}

// h0b[n] = bf16(concat(shape_emb[x[n,0]], color_emb[x[n,1]]))  -- 8 elems/thread
__global__ void embed_bf16(const int* __restrict__ x,
                           const float* __restrict__ se, const float* __restrict__ ce,
                           unsigned short* __restrict__ hb, int n_nodes) {
    int tid = blockIdx.x * 256 + threadIdx.x;   // n_nodes*32
    if (tid >= n_nodes * 32) return;
    int n = tid >> 5, c = tid & 31;
    const float* src = (c < 16) ? (se + (size_t)x[n * 2] * EMB + c * 8)
                                : (ce + (size_t)x[n * 2 + 1] * EMB + (c - 16) * 8);
    float4 v0 = *(const float4*)src;
    float4 v1 = *(const float4*)(src + 4);
    ushort4 o0 = make_ushort4(f2bf(v0.x), f2bf(v0.y), f2bf(v0.z), f2bf(v0.w));
    ushort4 o1 = make_ushort4(f2bf(v1.x), f2bf(v1.y), f2bf(v1.z), f2bf(v1.w));
    *(ushort4*)(hb + (size_t)tid * 8)     = o0;
    *(ushort4*)(hb + (size_t)tid * 8 + 4) = o1;
}

// ---------------------------------------------------------------- CSR build

__global__ void count_deg(const int* __restrict__ dst, int* __restrict__ deg, int E) {
    int e = blockIdx.x * 256 + threadIdx.x;
    if (e < E) atomicAdd(&deg[dst[e]], 1);
}

__global__ void scan_block(const int* __restrict__ deg, int* __restrict__ rowptr,
                           int* __restrict__ bsums, int n) {
    __shared__ int s[256];
    int t = threadIdx.x;
    int i = blockIdx.x * 256 + t;
    int v = (i < n) ? deg[i] : 0;
    s[t] = v; __syncthreads();
    for (int off = 1; off < 256; off <<= 1) {
        int x = (t >= off) ? s[t - off] : 0;
        __syncthreads(); s[t] += x; __syncthreads();
    }
    if (i < n) rowptr[i] = s[t] - v;
    if (t == 255) bsums[blockIdx.x] = s[255];
}

__global__ void scan_sums(int* __restrict__ bsums, int nb, int* __restrict__ rowptr,
                          int n, int E) {
    __shared__ int s[256];
    int t = threadIdx.x;
    int v = (t < nb) ? bsums[t] : 0;
    s[t] = v; __syncthreads();
    for (int off = 1; off < 256; off <<= 1) {
        int x = (t >= off) ? s[t - off] : 0;
        __syncthreads(); s[t] += x; __syncthreads();
    }
    if (t < nb) bsums[t] = s[t] - v;
    if (t == 0) rowptr[n] = E;
}

__global__ void scan_add(int* __restrict__ rowptr, const int* __restrict__ bsums, int n) {
    int i = blockIdx.x * 256 + threadIdx.x;
    if (i < n) rowptr[i] += bsums[i >> 8];
}

__global__ void fill_csr(const int* __restrict__ src, const int* __restrict__ dst,
                         const int* __restrict__ rowptr, int* __restrict__ cursor,
                         int* __restrict__ csr, int E) {
    int e = blockIdx.x * 256 + threadIdx.x;
    if (e >= E) return;
    int d = dst[e];
    int pos = rowptr[d] + atomicAdd(&cursor[d], 1);
    csr[pos] = src[e];
}

// ---------------------------------------------------------------- mean aggregation
// one wave per node; lane l owns bf16 chunk [l*4 .. l*4+3] (8 B gather per lane).
// unroll-4: 4 gathers in flight per wave to cover load latency.
__global__ void aggregate_bf16(const unsigned short* __restrict__ hb,
                               const int* __restrict__ rowptr, const int* __restrict__ csr,
                               float* __restrict__ agg, int n_nodes) {
    int wid = (blockIdx.x * 256 + threadIdx.x) >> 6;
    int lane = threadIdx.x & 63;
    if (wid >= n_nodes) return;
    int beg = rowptr[wid], end = rowptr[wid + 1];
    float a0 = 0.f, a1 = 0.f, a2 = 0.f, a3 = 0.f;
    int k = beg;
    for (; k + 3 < end; k += 4) {
        int s0 = csr[k], s1 = csr[k + 1], s2 = csr[k + 2], s3 = csr[k + 3];
        ushort4 u0 = *(const ushort4*)(hb + (size_t)s0 * DIM + lane * 4);
        ushort4 u1 = *(const ushort4*)(hb + (size_t)s1 * DIM + lane * 4);
        ushort4 u2 = *(const ushort4*)(hb + (size_t)s2 * DIM + lane * 4);
        ushort4 u3 = *(const ushort4*)(hb + (size_t)s3 * DIM + lane * 4);
        a0 += bf2f(u0.x) + bf2f(u1.x) + bf2f(u2.x) + bf2f(u3.x);
        a1 += bf2f(u0.y) + bf2f(u1.y) + bf2f(u2.y) + bf2f(u3.y);
        a2 += bf2f(u0.z) + bf2f(u1.z) + bf2f(u2.z) + bf2f(u3.z);
        a3 += bf2f(u0.w) + bf2f(u1.w) + bf2f(u2.w) + bf2f(u3.w);
    }
    for (; k < end; ++k) {
        ushort4 u = *(const ushort4*)(hb + (size_t)csr[k] * DIM + lane * 4);
        a0 += bf2f(u.x); a1 += bf2f(u.y); a2 += bf2f(u.z); a3 += bf2f(u.w);
    }
    int d = end - beg;
    float inv = 1.0f / (float)(d > 1 ? d : 1);
    float4 o; o.x = a0 * inv; o.y = a1 * inv; o.z = a2 * inv; o.w = a3 * inv;
    *(float4*)(agg + (size_t)wid * DIM + lane * 4) = o;
}

// ---------------------------------------------------------------- MFMA SAGE GEMM
// Hout[m,n] = relu( sum_k Agg[m,k]*Wl[n,k] + Hin[m,k]*Wr[n,k] + bias[n] )
// Agg fp32 (hi/lo split, 3 MFMA); Hin bf16 exact (lo==0, 2 MFMA).
// BM=64, BN=256 (full N), BK=32; 4 waves, one 64x64 tile each.
__global__ void __launch_bounds__(256)
gemm_mfma(const float* __restrict__ Agg, const unsigned short* __restrict__ Hinb,
          const unsigned short* __restrict__ Bhi, const unsigned short* __restrict__ Blo,
          const float* __restrict__ bias,
          float* __restrict__ Houtf, unsigned short* __restrict__ Houtb, int M) {
    __shared__ __align__(16) unsigned short As_hi[64 * 40];   // [row][k(32)+pad(8)]
    __shared__ __align__(16) unsigned short As_lo[64 * 40];

    const int t = threadIdx.x;
    const int w = t >> 6, lane = t & 63;
    const int lrow = lane & 15, koct = lane >> 4;
    const int nw = w * 64;
    const int m0 = blockIdx.x * 64;

    float4v acc[4][4];
#pragma unroll
    for (int i = 0; i < 4; ++i)
#pragma unroll
        for (int j = 0; j < 4; ++j) acc[i][j] = (float4v){0.f, 0.f, 0.f, 0.f};

    const int sr = t >> 2;            // staging row 0..63
    const int sc = (t & 3) * 8;       // staging k-offset 0,8,16,24
    const int gr = m0 + sr;
    const bool valid = (gr < M);

    // ---- phase 1: K = 0..255  (Agg, fp32 -> hi/lo, 3 MFMAs) ----
#pragma unroll 1
    for (int kt = 0; kt < 8; ++kt) {
        const float* __restrict__ Ap = Agg + (size_t)gr * DIM + (kt * 32 + sc);
        float4 v0 = make_float4(0.f, 0.f, 0.f, 0.f), v1 = v0;
        if (valid) { v0 = *(const float4*)Ap; v1 = *(const float4*)(Ap + 4); }
        float fv[8] = {v0.x, v0.y, v0.z, v0.w, v1.x, v1.y, v1.z, v1.w};
        unsigned short hs[8], ls[8];
#pragma unroll
        for (int i = 0; i < 8; ++i) {
            hs[i] = f2bf(fv[i]);
            ls[i] = f2bf(fv[i] - bf2f(hs[i]));
        }
        *(ushort4*)&As_hi[sr * 40 + sc]     = make_ushort4(hs[0], hs[1], hs[2], hs[3]);
        *(ushort4*)&As_hi[sr * 40 + sc + 4] = make_ushort4(hs[4], hs[5], hs[6], hs[7]);
        *(ushort4*)&As_lo[sr * 40 + sc]     = make_ushort4(ls[0], ls[1], ls[2], ls[3]);
        *(ushort4*)&As_lo[sr * 40 + sc + 4] = make_ushort4(ls[4], ls[5], ls[6], ls[7]);
        __syncthreads();

        const int kg = kt * 4 + koct;
        short8v bh[4], bl[4], ah[4], al[4];
#pragma unroll
        for (int nt = 0; nt < 4; ++nt) {
            size_t bofs = ((size_t)kg * 256 + (nw + nt * 16 + lrow)) * 8;
            bh[nt] = *(const short8v*)(Bhi + bofs);
            bl[nt] = *(const short8v*)(Blo + bofs);
        }
#pragma unroll
        for (int mt = 0; mt < 4; ++mt) {
            int aofs = (mt * 16 + lrow) * 40 + koct * 8;
            ah[mt] = *(const short8v*)&As_hi[aofs];
            al[mt] = *(const short8v*)&As_lo[aofs];
        }
#pragma unroll
        for (int mt = 0; mt < 4; ++mt)
#pragma unroll
            for (int nt = 0; nt < 4; ++nt) {
                acc[mt][nt] = __builtin_amdgcn_mfma_f32_16x16x32_bf16(ah[mt], bh[nt], acc[mt][nt], 0, 0, 0);
                acc[mt][nt] = __builtin_amdgcn_mfma_f32_16x16x32_bf16(ah[mt], bl[nt], acc[mt][nt], 0, 0, 0);
                acc[mt][nt] = __builtin_amdgcn_mfma_f32_16x16x32_bf16(al[mt], bh[nt], acc[mt][nt], 0, 0, 0);
            }
        __syncthreads();
    }

    // ---- phase 2: K = 256..511  (Hin bf16 exact, lo==0, 2 MFMAs) ----
#pragma unroll 1
    for (int kt = 8; kt < 16; ++kt) {
        const unsigned short* __restrict__ Hp =
            Hinb + (size_t)gr * DIM + ((kt - 8) * 32 + sc);
        short8v hv = (short8v){0,0,0,0,0,0,0,0};
        if (valid) hv = *(const short8v*)Hp;
        *(short8v*)&As_hi[sr * 40 + sc] = hv;
        __syncthreads();

        const int kg = kt * 4 + koct;
        short8v bh[4], bl[4], ah[4];
#pragma unroll
        for (int nt = 0; nt < 4; ++nt) {
            size_t bofs = ((size_t)kg * 256 + (nw + nt * 16 + lrow)) * 8;
            bh[nt] = *(const short8v*)(Bhi + bofs);
            bl[nt] = *(const short8v*)(Blo + bofs);
        }
#pragma unroll
        for (int mt = 0; mt < 4; ++mt)
            ah[mt] = *(const short8v*)&As_hi[(mt * 16 + lrow) * 40 + koct * 8];
#pragma unroll
        for (int mt = 0; mt < 4; ++mt)
#pragma unroll
            for (int nt = 0; nt < 4; ++nt) {
                acc[mt][nt] = __builtin_amdgcn_mfma_f32_16x16x32_bf16(ah[mt], bh[nt], acc[mt][nt], 0, 0, 0);
                acc[mt][nt] = __builtin_amdgcn_mfma_f32_16x16x32_bf16(ah[mt], bl[nt], acc[mt][nt], 0, 0, 0);
            }
        __syncthreads();
    }

    // ---- epilogue: bias + relu; C/D map col=lane&15, row=(lane>>4)*4+reg ----
    float bv[4];
#pragma unroll
    for (int nt = 0; nt < 4; ++nt) bv[nt] = bias[nw + nt * 16 + lrow];

#pragma unroll
    for (int mt = 0; mt < 4; ++mt) {
#pragma unroll
        for (int r = 0; r < 4; ++r) {
            int grow = m0 + mt * 16 + koct * 4 + r;
            if (grow >= M) continue;
#pragma unroll
            for (int nt = 0; nt < 4; ++nt) {
                float vv = fmaxf(acc[mt][nt][r] + bv[nt], 0.f);
                int col = nw + nt * 16 + lrow;
                if (Houtf) Houtf[(size_t)grow * DIM + col] = vv;
                if (Houtb) Houtb[(size_t)grow * DIM + col] = f2bf(vv);
            }
        }
    }
}

// ---------------------------------------------------------------- pooling + head

__global__ void pool_kernel(const float* __restrict__ h, const int* __restrict__ batch,
                            float* __restrict__ hg, int n_nodes) {
    int g = blockIdx.x;
    int t = threadIdx.x;
    int lo = 0, hi = n_nodes;
    while (lo < hi) { int mid = (lo + hi) >> 1; if (batch[mid] < g) lo = mid + 1; else hi = mid; }
    int start = lo;
    hi = n_nodes;
    while (lo < hi) { int mid = (lo + hi) >> 1; if (batch[mid] < g + 1) lo = mid + 1; else hi = mid; }
    int end = lo;
    float acc = 0.f;
    for (int n = start; n < end; ++n) acc += h[(size_t)n * DIM + t];
    int c = end - start;
    hg[g * DIM + t] = acc / (float)(c > 1 ? c : 1);
}

__global__ void head_kernel(const float* __restrict__ hg, const float* __restrict__ wc,
                            const float* __restrict__ bc, float* __restrict__ out, int total) {
    int tid = blockIdx.x * 256 + threadIdx.x;
    if (tid >= total) return;
    int g = tid >> 5, c = tid & 31;
    const float* hr = hg + (size_t)g * DIM;
    const float* wr = wc + (size_t)c * DIM;
    float acc = bc[c];
    for (int k = 0; k < DIM; ++k) acc = fmaf(hr[k], wr[k], acc);
    out[tid] = acc;
}

// ---------------------------------------------------------------- launch

extern "C" void kernel_launch(void* const* d_in, const int* in_sizes, int n_in,
                              void* d_out, int out_size, void* d_ws, size_t ws_size,
                              hipStream_t stream) {
    const int* x      = (const int*)d_in[0];
    const int* ei     = (const int*)d_in[1];
    const int* batch  = (const int*)d_in[2];
    const float* se   = (const float*)d_in[3];
    const float* ce   = (const float*)d_in[4];
    const float* w1l  = (const float*)d_in[5];
    const float* b1l  = (const float*)d_in[6];
    const float* w1r  = (const float*)d_in[7];
    const float* w2l  = (const float*)d_in[8];
    const float* b2l  = (const float*)d_in[9];
    const float* w2r  = (const float*)d_in[10];
    const float* wc   = (const float*)d_in[11];
    const float* bc   = (const float*)d_in[12];
    float* out = (float*)d_out;

    const int N = in_sizes[0] / 2;
    const int E = in_sizes[1] / 2;
    const int G = out_size / NCLS;
    const int* src = ei;
    const int* dst = ei + E;

    // workspace carve-up
    float* agg = (float*)d_ws;                              // N*256 f32
    float* h2  = agg + (size_t)N * DIM;                     // N*256 f32
    unsigned short* h0b = (unsigned short*)(h2 + (size_t)N * DIM); // N*256 bf16
    unsigned short* h1b = h0b + (size_t)N * DIM;            // N*256 bf16
    unsigned short* B1hi = h1b + (size_t)N * DIM;           // 512*256 each
    unsigned short* B1lo = B1hi + 131072;
    unsigned short* B2hi = B1lo + 131072;
    unsigned short* B2lo = B2hi + 131072;
    float* hg  = (float*)(B2lo + 131072);                   // G*256
    int* deg    = (int*)(hg + (size_t)G * DIM);             // N
    int* rowptr = deg + N;                                  // N+1
    int* cursor = rowptr + (N + 1);                         // N
    int* csr    = cursor + N;                               // E
    int* bsums  = csr + E;                                  // <=256

    hipMemsetAsync(deg, 0, (size_t)(3 * N + 1) * sizeof(int), stream);

    embed_bf16<<<(N * 32 + 255) / 256, 256, 0, stream>>>(x, se, ce, h0b, N);

    int eblocks = (E + 255) / 256;
    count_deg<<<eblocks, 256, 0, stream>>>(dst, deg, E);
    int sblocks = (N + 255) / 256;
    scan_block<<<sblocks, 256, 0, stream>>>(deg, rowptr, bsums, N);
    scan_sums<<<1, 256, 0, stream>>>(bsums, sblocks, rowptr, N, E);
    scan_add<<<sblocks, 256, 0, stream>>>(rowptr, bsums, N);
    fill_csr<<<eblocks, 256, 0, stream>>>(src, dst, rowptr, cursor, csr, E);

    build_bq<<<512, 256, 0, stream>>>(w1l, w1r, B1hi, B1lo);
    build_bq<<<512, 256, 0, stream>>>(w2l, w2r, B2hi, B2lo);

    int gblocks = (N + 63) / 64;
    int ablocks = (N * 64 + 255) / 256;

    // layer 1: h0b -> agg -> h1b (bf16 out)
    aggregate_bf16<<<ablocks, 256, 0, stream>>>(h0b, rowptr, csr, agg, N);
    gemm_mfma<<<gblocks, 256, 0, stream>>>(agg, h0b, B1hi, B1lo, b1l, nullptr, h1b, N);

    // layer 2: h1b -> agg -> h2 (fp32 out for pooling)
    aggregate_bf16<<<ablocks, 256, 0, stream>>>(h1b, rowptr, csr, agg, N);
    gemm_mfma<<<gblocks, 256, 0, stream>>>(agg, h1b, B2hi, B2lo, b2l, h2, nullptr, N);

    pool_kernel<<<G, 256, 0, stream>>>(h2, batch, hg, N);
    head_kernel<<<(G * NCLS + 255) / 256, 256, 0, stream>>>(hg, wc, bc, out, G * NCLS);
}